// Round 6
// baseline (235.845 us; speedup 1.0000x reference)
//
#include <hip/hip_runtime.h>

typedef unsigned short UST;
typedef unsigned int u32;
typedef __attribute__((ext_vector_type(8))) short short8;
typedef __attribute__((ext_vector_type(4))) float f32x4;

#define HPAD 258
#define CIN 256
#define COUT 512
#define KTOT 2304  // 256*9
#define NT 36      // K-tiles of 64

// workspace partition (bytes)
#define WB_BYTES (COUT * KTOT * 2)
#define XBT_OFF  WB_BYTES
#define XBT_BYTES (HPAD * HPAD * CIN * 2)
#define ABSM_OFF (XBT_OFF + XBT_BYTES)
#define ABSM_BYTES (HPAD * HPAD * 4)
#define INK_OFF  (ABSM_OFF + ABSM_BYTES)

__device__ __forceinline__ UST f2bf(float f) {
  union { float f; u32 u; } c; c.f = f;
  u32 u = c.u;
  u += 0x7FFFu + ((u >> 16) & 1u);
  return (UST)(u >> 16);
}

__device__ __forceinline__ void gload_lds16(const void* g, void* l) {
  __builtin_amdgcn_global_load_lds(
      (const __attribute__((address_space(1))) u32*)g,
      (__attribute__((address_space(3))) u32*)l, 16, 0, 0);
}

// ---- kernel 1: alpha-fold + reorder weights to [co][khkw*256+ci] bf16 ----
__global__ __launch_bounds__(256) void k_prep_w(const float* __restrict__ w,
                                                UST* __restrict__ wb) {
  int co = blockIdx.x;
  int ci = threadIdx.x;
  const float* wr = w + co * KTOT + ci * 9;
  float v[9];
  float s = 0.f;
#pragma unroll
  for (int j = 0; j < 9; ++j) { v[j] = wr[j]; s += v[j]; }
  __shared__ float red[256];
  red[ci] = s;
  __syncthreads();
#pragma unroll
  for (int off = 128; off > 0; off >>= 1) {
    if (ci < off) red[ci] += red[ci + off];
    __syncthreads();
  }
  float alpha = red[0] * (1.0f / 2304.0f);
  UST* wo = wb + co * KTOT + ci;
#pragma unroll
  for (int j = 0; j < 9; ++j) wo[j * 256] = f2bf(v[j] * alpha);
}

// ---- kernel 2: binarize + NCHW->NHWC transpose + channel-mean |x| ----
__global__ __launch_bounds__(256) void k_binz(const float* __restrict__ x,
                                              UST* __restrict__ xbt,
                                              float* __restrict__ absm) {
  int hp = blockIdx.x;
  int wt = blockIdx.y;
  int wpl = threadIdx.x & 63;
  int chunk = threadIdx.x >> 6;
  int wp = wt * 64 + wpl;
  bool valid = wp < HPAD;
  int hx = hp - 1, wx = wp - 1;
  bool inb = valid && ((unsigned)hx < 256u) && ((unsigned)wx < 256u);
  float asum = 0.f;
  u32 pk[32];
#pragma unroll
  for (int c2 = 0; c2 < 32; ++c2) {
    int ci = chunk * 64 + c2 * 2;
    float v0 = 1.0f, v1 = 1.0f;
    if (inb) {
      v0 = x[(unsigned)ci * 65536u + (unsigned)(hx * 256 + wx)];
      v1 = x[(unsigned)(ci + 1) * 65536u + (unsigned)(hx * 256 + wx)];
    }
    asum += fabsf(v0) + fabsf(v1);
    u32 s0 = (v0 >= 0.f) ? 0x3F80u : 0xBF80u;
    u32 s1 = (v1 >= 0.f) ? 0x3F80u : 0xBF80u;
    pk[c2] = s0 | (s1 << 16);
  }
  if (valid) {
    uint4* dst = (uint4*)(xbt + ((unsigned)(hp * HPAD + wp) * 256u + chunk * 64));
#pragma unroll
    for (int g = 0; g < 8; ++g)
      dst[g] = make_uint4(pk[g * 4], pk[g * 4 + 1], pk[g * 4 + 2], pk[g * 4 + 3]);
  }
  __shared__ float red[4][64];
  red[chunk][wpl] = asum;
  __syncthreads();
  if (chunk == 0 && valid) {
    float tot = red[0][wpl] + red[1][wpl] + red[2][wpl] + red[3][wpl];
    absm[hp * HPAD + wp] = tot * (1.0f / 256.0f);
  }
}

// ---- kernel 3: 3x3 box filter / 9 ----
__global__ __launch_bounds__(256) void k_inputk(const float* __restrict__ absm,
                                                float* __restrict__ inK) {
  int h = blockIdx.x, w = threadIdx.x;
  float s = 0.f;
#pragma unroll
  for (int dh = 0; dh < 3; ++dh)
#pragma unroll
    for (int dw = 0; dw < 3; ++dw) s += absm[(h + dh) * HPAD + (w + dw)];
  inK[h * 256 + w] = s * (1.0f / 9.0f);
}

// ---- kernel 4: 256x256-tile implicit-GEMM conv ----
// A (weights) in LDS: 2 bufs x 2 planes x [256 rows][32 k] bf16, superrow-XOR
// swizzled (verified conflict-free), staged via global_load_lds (4 insts/tile).
// B (pixels) DIRECT global->register: per wave 8 x 16B loads per tile
// (n=0..3 x ks=0..1), issued one tile ahead. This removes B from the LDS
// port (192KB->128KB per tile per CU) and puts it on the VMEM pipe, which
// overlaps both the LDS port and the matrix pipe.
// One barrier per tile; waves drift within the tile (T5 role-split).
#define MM(a, b, c) __builtin_amdgcn_mfma_f32_16x16x32_bf16(a, b, c, 0, 0, 0)

#define A_LDS(B, P) (lds + (B) * 32768 + (P) * 16384)
#define RD_A(B, P, M) (*(const short8*)(A_LDS(B, P) + swzA[M]))

#define STAGE_A(SRC, P, B) do { \
    const char* s_ = (SRC) + (P) * 64; \
    char* d_ = A_LDS(B, P) + wv * 1024; \
    gload_lds16(s_ + aoff0, d_); \
    gload_lds16(s_ + aoff1, d_ + 8192); } while (0)

#define CLUSTER(AF, BARR, KS) \
  _Pragma("unroll") for (int m = 0; m < 8; ++m) \
  _Pragma("unroll") for (int n = 0; n < 4; ++n) \
    acc[m][n] = MM(AF[m], BARR[2 * n + (KS)], acc[m][n]);

#define LOADB(BNXT, BSRC) \
  _Pragma("unroll") for (int n = 0; n < 4; ++n) { \
    BNXT[2 * n]     = *(const short8*)((BSRC) + boffn[n]); \
    BNXT[2 * n + 1] = *(const short8*)((BSRC) + boffn[n] + 64); \
  }

// body for tile t: consumes BCUR regs + A buf CUR; prefetches t+1
#define BODY(CUR, BCUR, BNXT, ASTAGE, BSTAGE) do { \
  LOADB(BNXT, (BSTAGE)); \
  STAGE_A((ASTAGE), 0, (CUR) ^ 1); STAGE_A((ASTAGE), 1, (CUR) ^ 1); \
  __builtin_amdgcn_sched_barrier(0); \
  { short8 AF[8]; \
    _Pragma("unroll") for (int m = 0; m < 8; ++m) AF[m] = RD_A(CUR, 0, m); \
    __builtin_amdgcn_s_setprio(1); \
    CLUSTER(AF, BCUR, 0); \
    __builtin_amdgcn_s_setprio(0); } \
  { short8 AF[8]; \
    _Pragma("unroll") for (int m = 0; m < 8; ++m) AF[m] = RD_A(CUR, 1, m); \
    __builtin_amdgcn_s_setprio(1); \
    CLUSTER(AF, BCUR, 1); \
    __builtin_amdgcn_s_setprio(0); } \
  asm volatile("s_waitcnt lgkmcnt(0)" ::: "memory"); \
  asm volatile("s_waitcnt vmcnt(0)" ::: "memory"); \
  __builtin_amdgcn_s_barrier(); \
} while (0)

#define BODY_LAST(CUR, BCUR) do { \
  { short8 AF[8]; \
    _Pragma("unroll") for (int m = 0; m < 8; ++m) AF[m] = RD_A(CUR, 0, m); \
    __builtin_amdgcn_s_setprio(1); \
    CLUSTER(AF, BCUR, 0); \
    __builtin_amdgcn_s_setprio(0); } \
  { short8 AF[8]; \
    _Pragma("unroll") for (int m = 0; m < 8; ++m) AF[m] = RD_A(CUR, 1, m); \
    __builtin_amdgcn_s_setprio(1); \
    CLUSTER(AF, BCUR, 1); \
    __builtin_amdgcn_s_setprio(0); } \
} while (0)

__global__ __launch_bounds__(512, 2) void k_conv8(const UST* __restrict__ wb,
                                                  const UST* __restrict__ xbt,
                                                  const float* __restrict__ inK,
                                                  float* __restrict__ out) {
  __shared__ __align__(16) char lds[65536];
  int tid = threadIdx.x;
  int lane = tid & 63;
  int wv = tid >> 6;
  int wm = wv >> 2, wn = wv & 3;
  int bid = blockIdx.x;
  int bs = (bid & 7) * 64 + (bid >> 3);  // XCD-bijective swizzle (512 % 8 == 0)
  int mt = bs & 1;
  int h = bs >> 1;
  int co0 = mt << 8;

  // A staging per-thread offsets (inverse-swizzled global source, linear dest)
  int aoff0, aoff1;
  {
    u32 ql0 = (u32)tid * 16u, ql1 = (u32)(512 + tid) * 16u;
    u32 sr0 = ql0 >> 7, s0 = ((ql0 >> 4) & 7u) ^ (sr0 & 7u);
    u32 row0 = (sr0 << 1) | (s0 >> 2), q0 = s0 & 3u;
    u32 sr1 = ql1 >> 7, s1 = ((ql1 >> 4) & 7u) ^ (sr1 & 7u);
    u32 row1 = (sr1 << 1) | (s1 >> 2), q1 = s1 & 3u;
    aoff0 = (co0 + (int)row0) * 4608 + (int)q0 * 16;
    aoff1 = (co0 + (int)row1) * 4608 + (int)q1 * 16;
  }
  // A ds_read swizzled offsets within a plane
  int swzA[8];
#pragma unroll
  for (int m = 0; m < 8; ++m) {
    u32 row = (u32)(wm * 128 + m * 16 + (lane & 15));
    u32 q = (u32)(lane >> 4);
    u32 sr = row >> 1, s = ((row & 1u) << 2) | q;
    swzA[m] = (int)(sr * 128u + (s ^ (sr & 7u)) * 16u);
  }
  // B per-lane global offsets (bytes within a tile's B base)
  int boffn[4];
#pragma unroll
  for (int n = 0; n < 4; ++n)
    boffn[n] = (wn * 64 + n * 16 + (lane & 15)) * 512 + (lane >> 4) * 16;

  const char* wb_b = (const char*)wb;
  const char* xbt_b = (const char*)xbt;

  f32x4 acc[8][4];
#pragma unroll
  for (int m = 0; m < 8; ++m)
#pragma unroll
    for (int n = 0; n < 4; ++n) acc[m][n] = (f32x4){0.f, 0.f, 0.f, 0.f};

  short8 BA[8], BB[8];

  // prologue: B(t=0) -> BA regs; A(t=0) -> buf 0
  {
    const char* b0src = xbt_b + (h * HPAD) * 512;  // kh=0, kw=0, c0=0
    LOADB(BA, b0src);
    STAGE_A(wb_b, 0, 0); STAGE_A(wb_b, 1, 0);
  }
  asm volatile("s_waitcnt vmcnt(0)" ::: "memory");
  __builtin_amdgcn_s_barrier();

  // main: 8 khkw groups of 4 tiles (t = 0..31)
  int kh = 0, kw = 0;
  const char* bcur = xbt_b + (h * HPAD) * 512;
  for (int it = 0; it < 8; ++it) {
    int nkw = kw + 1, nkh = kh;
    if (nkw == 3) { nkw = 0; ++nkh; }
    const char* bnext = xbt_b + ((h + nkh) * HPAD + nkw) * 512;
    const char* acur = wb_b + it * 512;
    BODY(0, BA, BB, acur + 128, bcur + 128);  // t=4it+0, prefetch t+1
    BODY(1, BB, BA, acur + 256, bcur + 256);  // t=4it+1
    BODY(0, BA, BB, acur + 384, bcur + 384);  // t=4it+2
    BODY(1, BB, BA, acur + 512, bnext);       // t=4it+3, prefetch next group
    kh = nkh; kw = nkw; bcur = bnext;
  }
  // khkw = 8 (kh=2, kw=2): t = 32..35
  {
    const char* acur = wb_b + 8 * 512;
    BODY(0, BA, BB, acur + 128, bcur + 128);  // t=32
    BODY(1, BB, BA, acur + 256, bcur + 256);  // t=33
    BODY(0, BA, BB, acur + 384, bcur + 384);  // t=34
    BODY_LAST(1, BB);                         // t=35
  }

  // epilogue: scale by input_K, write NCHW
  int col = lane & 15, rg = lane >> 4;
  int pixbase = h * 256;
#pragma unroll
  for (int n = 0; n < 4; ++n) {
    int w = wn * 64 + n * 16 + col;
    float kv = inK[pixbase + w];
#pragma unroll
    for (int m = 0; m < 8; ++m) {
      int co = co0 + wm * 128 + m * 16 + rg * 4;
      float* o = out + (u32)co * 65536u + (u32)(pixbase + w);
#pragma unroll
      for (int r = 0; r < 4; ++r) o[(u32)r * 65536u] = acc[m][n][r] * kv;
    }
  }
}

extern "C" void kernel_launch(void* const* d_in, const int* in_sizes, int n_in,
                              void* d_out, int out_size, void* d_ws, size_t ws_size,
                              hipStream_t stream) {
  const float* x = (const float*)d_in[0];
  const float* w = (const float*)d_in[1];
  float* out = (float*)d_out;
  char* ws = (char*)d_ws;
  UST* wb = (UST*)ws;
  UST* xbt = (UST*)(ws + XBT_OFF);
  float* absm = (float*)(ws + ABSM_OFF);
  float* inK = (float*)(ws + INK_OFF);

  k_prep_w<<<COUT, 256, 0, stream>>>(w, wb);
  k_binz<<<dim3(HPAD, 5), 256, 0, stream>>>(x, xbt, absm);
  k_inputk<<<256, 256, 0, stream>>>(absm, inK);
  k_conv8<<<512, 512, 0, stream>>>(wb, xbt, inK, out);
}

// Round 7
// 190.672 us; speedup vs baseline: 1.2369x; 1.2369x over previous
//
#include <hip/hip_runtime.h>

typedef unsigned short UST;
typedef unsigned int u32;
typedef __attribute__((ext_vector_type(8))) short short8;
typedef __attribute__((ext_vector_type(4))) float f32x4;

#define HPAD 258
#define CIN 256
#define COUT 512
#define KTOT 2304  // 256*9
#define NT 36      // K-tiles of 64

// workspace partition (bytes)
#define WB_BYTES (COUT * KTOT * 2)
#define XBT_OFF  WB_BYTES
#define XBT_BYTES (HPAD * HPAD * CIN * 2)
#define ABSM_OFF (XBT_OFF + XBT_BYTES)
#define ABSM_BYTES (HPAD * HPAD * 4)
#define INK_OFF  (ABSM_OFF + ABSM_BYTES)

__device__ __forceinline__ UST f2bf(float f) {
  union { float f; u32 u; } c; c.f = f;
  u32 u = c.u;
  u += 0x7FFFu + ((u >> 16) & 1u);
  return (UST)(u >> 16);
}

__device__ __forceinline__ void gload_lds16(const void* g, void* l) {
  __builtin_amdgcn_global_load_lds(
      (const __attribute__((address_space(1))) u32*)g,
      (__attribute__((address_space(3))) u32*)l, 16, 0, 0);
}

// ---- kernel 1: alpha-fold + reorder weights to [co][khkw*256+ci] bf16 ----
__global__ __launch_bounds__(256) void k_prep_w(const float* __restrict__ w,
                                                UST* __restrict__ wb) {
  int co = blockIdx.x;
  int ci = threadIdx.x;
  const float* wr = w + co * KTOT + ci * 9;
  float v[9];
  float s = 0.f;
#pragma unroll
  for (int j = 0; j < 9; ++j) { v[j] = wr[j]; s += v[j]; }
  __shared__ float red[256];
  red[ci] = s;
  __syncthreads();
#pragma unroll
  for (int off = 128; off > 0; off >>= 1) {
    if (ci < off) red[ci] += red[ci + off];
    __syncthreads();
  }
  float alpha = red[0] * (1.0f / 2304.0f);
  UST* wo = wb + co * KTOT + ci;
#pragma unroll
  for (int j = 0; j < 9; ++j) wo[j * 256] = f2bf(v[j] * alpha);
}

// ---- kernel 2: binarize + NCHW->NHWC transpose + channel-mean |x| ----
__global__ __launch_bounds__(256) void k_binz(const float* __restrict__ x,
                                              UST* __restrict__ xbt,
                                              float* __restrict__ absm) {
  int hp = blockIdx.x;
  int wt = blockIdx.y;
  int wpl = threadIdx.x & 63;
  int chunk = threadIdx.x >> 6;
  int wp = wt * 64 + wpl;
  bool valid = wp < HPAD;
  int hx = hp - 1, wx = wp - 1;
  bool inb = valid && ((unsigned)hx < 256u) && ((unsigned)wx < 256u);
  float asum = 0.f;
  u32 pk[32];
#pragma unroll
  for (int c2 = 0; c2 < 32; ++c2) {
    int ci = chunk * 64 + c2 * 2;
    float v0 = 1.0f, v1 = 1.0f;
    if (inb) {
      v0 = x[(unsigned)ci * 65536u + (unsigned)(hx * 256 + wx)];
      v1 = x[(unsigned)(ci + 1) * 65536u + (unsigned)(hx * 256 + wx)];
    }
    asum += fabsf(v0) + fabsf(v1);
    u32 s0 = (v0 >= 0.f) ? 0x3F80u : 0xBF80u;
    u32 s1 = (v1 >= 0.f) ? 0x3F80u : 0xBF80u;
    pk[c2] = s0 | (s1 << 16);
  }
  if (valid) {
    uint4* dst = (uint4*)(xbt + ((unsigned)(hp * HPAD + wp) * 256u + chunk * 64));
#pragma unroll
    for (int g = 0; g < 8; ++g)
      dst[g] = make_uint4(pk[g * 4], pk[g * 4 + 1], pk[g * 4 + 2], pk[g * 4 + 3]);
  }
  __shared__ float red[4][64];
  red[chunk][wpl] = asum;
  __syncthreads();
  if (chunk == 0 && valid) {
    float tot = red[0][wpl] + red[1][wpl] + red[2][wpl] + red[3][wpl];
    absm[hp * HPAD + wp] = tot * (1.0f / 256.0f);
  }
}

// ---- kernel 3: 3x3 box filter / 9 ----
__global__ __launch_bounds__(256) void k_inputk(const float* __restrict__ absm,
                                                float* __restrict__ inK) {
  int h = blockIdx.x, w = threadIdx.x;
  float s = 0.f;
#pragma unroll
  for (int dh = 0; dh < 3; ++dh)
#pragma unroll
    for (int dw = 0; dw < 3; ++dw) s += absm[(h + dh) * HPAD + (w + dw)];
  inK[h * 256 + w] = s * (1.0f / 9.0f);
}

// ---- kernel 4: 128x128-tile implicit-GEMM conv, 2 blocks/CU for TLP overlap ----
// Per block: 4 waves (2x2), BK=64, LDS = 64 KiB:
//   A planes: lds + b*16384 + P*8192      [b=buffer, P=K-half]
//   B planes: lds + 32768 + b*16384 + P*8192
// Each plane: 128 rows x 32 k bf16, superrow-XOR swizzled (verified 0-conflict):
//   (row, q[16B slot]) -> sr=row>>1, s=((row&1)<<2)|q, byte = sr*128 + (s^(sr&7))*16
// With 2 resident blocks/CU, one block's read-burst/barrier-drain overlaps the
// other block's MFMA stream via hardware wave arbitration (no lockstep).
#define MM(a, b, c) __builtin_amdgcn_mfma_f32_16x16x32_bf16(a, b, c, 0, 0, 0)

#define A_LDS(B, P) (lds + (B) * 16384 + (P) * 8192)
#define B_LDS(B, P) (lds + 32768 + (B) * 16384 + (P) * 8192)
#define RD_A(B, P, M) (*(const short8*)(A_LDS(B, P) + swzA[M]))
#define RD_B(B, P, N) (*(const short8*)(B_LDS(B, P) + swzB[N]))

#define STAGE_A(SRC, P, BUF) do { \
    const char* s_ = (SRC) + (P) * 64; \
    char* d_ = A_LDS(BUF, P) + wv * 1024; \
    gload_lds16(s_ + aoff0, d_); \
    gload_lds16(s_ + aoff1, d_ + 4096); } while (0)

#define STAGE_B(SRC, P, BUF) do { \
    const char* s_ = (SRC) + (P) * 64; \
    char* d_ = B_LDS(BUF, P) + wv * 1024; \
    gload_lds16(s_ + boff0, d_); \
    gload_lds16(s_ + boff1, d_ + 4096); } while (0)

#define CL16(AA, BB) \
  _Pragma("unroll") for (int m = 0; m < 4; ++m) \
  _Pragma("unroll") for (int n = 0; n < 4; ++n) \
    acc[m][n] = MM(AA[m], BB[n], acc[m][n]);

// tile t reading buf CUR; stages tile TT1 into buf CUR^1
#define BODY(CUR, TT1) do { \
  short8 a0[4], b0[4], a1[4], b1[4]; \
  _Pragma("unroll") for (int n = 0; n < 4; ++n) b0[n] = RD_B(CUR, 0, n); \
  _Pragma("unroll") for (int m = 0; m < 4; ++m) a0[m] = RD_A(CUR, 0, m); \
  _Pragma("unroll") for (int n = 0; n < 4; ++n) b1[n] = RD_B(CUR, 1, n); \
  _Pragma("unroll") for (int m = 0; m < 4; ++m) a1[m] = RD_A(CUR, 1, m); \
  { int tt_ = (TT1); int khkw_ = tt_ >> 2; int kh_ = (khkw_ * 11) >> 5; \
    int kw_ = khkw_ - kh_ * 3; \
    const char* asrc_ = wb_b + tt_ * 128; \
    const char* bsrc_ = xbt_b + ((h + kh_) * HPAD + kw_ + w0) * 512 + (tt_ & 3) * 128; \
    STAGE_A(asrc_, 0, (CUR) ^ 1); STAGE_A(asrc_, 1, (CUR) ^ 1); \
    STAGE_B(bsrc_, 0, (CUR) ^ 1); STAGE_B(bsrc_, 1, (CUR) ^ 1); } \
  __builtin_amdgcn_sched_barrier(0); \
  __builtin_amdgcn_s_setprio(1); CL16(a0, b0); __builtin_amdgcn_s_setprio(0); \
  __builtin_amdgcn_s_setprio(1); CL16(a1, b1); __builtin_amdgcn_s_setprio(0); \
  asm volatile("s_waitcnt vmcnt(0)" ::: "memory"); \
  __builtin_amdgcn_s_barrier(); \
} while (0)

#define BODY_LAST(CUR) do { \
  short8 a0[4], b0[4], a1[4], b1[4]; \
  _Pragma("unroll") for (int n = 0; n < 4; ++n) b0[n] = RD_B(CUR, 0, n); \
  _Pragma("unroll") for (int m = 0; m < 4; ++m) a0[m] = RD_A(CUR, 0, m); \
  _Pragma("unroll") for (int n = 0; n < 4; ++n) b1[n] = RD_B(CUR, 1, n); \
  _Pragma("unroll") for (int m = 0; m < 4; ++m) a1[m] = RD_A(CUR, 1, m); \
  __builtin_amdgcn_s_setprio(1); CL16(a0, b0); __builtin_amdgcn_s_setprio(0); \
  __builtin_amdgcn_s_setprio(1); CL16(a1, b1); __builtin_amdgcn_s_setprio(0); \
} while (0)

__global__ __launch_bounds__(256, 2) void k_conv(const UST* __restrict__ wb,
                                                 const UST* __restrict__ xbt,
                                                 const float* __restrict__ inK,
                                                 float* __restrict__ out) {
  __shared__ __align__(16) char lds[65536];
  int tid = threadIdx.x;
  int lane = tid & 63;
  int wv = tid >> 6;            // 0..3
  int wm = wv >> 1, wn = wv & 1;
  int bid = blockIdx.x;
  int bs = (bid & 7) * 256 + (bid >> 3);  // XCD-bijective swizzle (2048 % 8 == 0)
  int mt = bs >> 9;             // co tile (4)
  int rem = bs & 511;
  int h = rem >> 1;
  int w0 = (rem & 1) << 7;
  int co0 = mt << 7;

  // staging per-thread offsets (inverse-swizzled global source, linear LDS dest)
  int aoff0, aoff1, boff0, boff1;
  {
    u32 ql0 = (u32)tid * 16u, ql1 = (u32)(256 + tid) * 16u;
    u32 sr0 = ql0 >> 7, s0 = ((ql0 >> 4) & 7u) ^ (sr0 & 7u);
    u32 row0 = (sr0 << 1) | (s0 >> 2), q0 = s0 & 3u;
    u32 sr1 = ql1 >> 7, s1 = ((ql1 >> 4) & 7u) ^ (sr1 & 7u);
    u32 row1 = (sr1 << 1) | (s1 >> 2), q1 = s1 & 3u;
    aoff0 = (co0 + (int)row0) * 4608 + (int)q0 * 16;
    aoff1 = (co0 + (int)row1) * 4608 + (int)q1 * 16;
    boff0 = (int)row0 * 512 + (int)q0 * 16;
    boff1 = (int)row1 * 512 + (int)q1 * 16;
  }
  // ds_read swizzled offsets within a plane
  int swzA[4], swzB[4];
#pragma unroll
  for (int m = 0; m < 4; ++m) {
    u32 row = (u32)(wm * 64 + m * 16 + (lane & 15));
    u32 q = (u32)(lane >> 4);
    u32 sr = row >> 1, s = ((row & 1u) << 2) | q;
    swzA[m] = (int)(sr * 128u + (s ^ (sr & 7u)) * 16u);
  }
#pragma unroll
  for (int n = 0; n < 4; ++n) {
    u32 row = (u32)(wn * 64 + n * 16 + (lane & 15));
    u32 q = (u32)(lane >> 4);
    u32 sr = row >> 1, s = ((row & 1u) << 2) | q;
    swzB[n] = (int)(sr * 128u + (s ^ (sr & 7u)) * 16u);
  }

  const char* wb_b = (const char*)wb;
  const char* xbt_b = (const char*)xbt;

  f32x4 acc[4][4];
#pragma unroll
  for (int m = 0; m < 4; ++m)
#pragma unroll
    for (int n = 0; n < 4; ++n) acc[m][n] = (f32x4){0.f, 0.f, 0.f, 0.f};

  // prologue: stage tile 0 into buf 0
  {
    const char* asrc_ = wb_b;
    const char* bsrc_ = xbt_b + (h * HPAD + w0) * 512;  // kh=0, kw=0, c-chunk 0
    STAGE_A(asrc_, 0, 0); STAGE_A(asrc_, 1, 0);
    STAGE_B(bsrc_, 0, 0); STAGE_B(bsrc_, 1, 0);
  }
  asm volatile("s_waitcnt vmcnt(0)" ::: "memory");
  __builtin_amdgcn_s_barrier();

  // tiles 0..33 in pairs, then 34 (stages 35), then 35
  for (int t = 0; t < 34; t += 2) {
    BODY(0, t + 1);
    BODY(1, t + 2);
  }
  BODY(0, 35);
  BODY_LAST(1);

  // epilogue: scale by input_K, write NCHW
  int col = lane & 15, rg = lane >> 4;
  int pixbase = h * 256;
#pragma unroll
  for (int n = 0; n < 4; ++n) {
    int w = w0 + wn * 64 + n * 16 + col;
    float kv = inK[pixbase + w];
#pragma unroll
    for (int m = 0; m < 4; ++m) {
      int co = co0 + wm * 64 + m * 16 + rg * 4;
      float* o = out + (u32)co * 65536u + (u32)(pixbase + w);
#pragma unroll
      for (int r = 0; r < 4; ++r) o[(u32)r * 65536u] = acc[m][n][r] * kv;
    }
  }
}

extern "C" void kernel_launch(void* const* d_in, const int* in_sizes, int n_in,
                              void* d_out, int out_size, void* d_ws, size_t ws_size,
                              hipStream_t stream) {
  const float* x = (const float*)d_in[0];
  const float* w = (const float*)d_in[1];
  float* out = (float*)d_out;
  char* ws = (char*)d_ws;
  UST* wb = (UST*)ws;
  UST* xbt = (UST*)(ws + XBT_OFF);
  float* absm = (float*)(ws + ABSM_OFF);
  float* inK = (float*)(ws + INK_OFF);

  k_prep_w<<<COUT, 256, 0, stream>>>(w, wb);
  k_binz<<<dim3(HPAD, 5), 256, 0, stream>>>(x, xbt, absm);
  k_inputk<<<256, 256, 0, stream>>>(absm, inK);
  k_conv<<<2048, 256, 0, stream>>>(wb, xbt, inK, out);
}

// Round 8
// 170.772 us; speedup vs baseline: 1.3811x; 1.1165x over previous
//
#include <hip/hip_runtime.h>

typedef unsigned short UST;
typedef unsigned int u32;
typedef __attribute__((ext_vector_type(8))) short short8;
typedef __attribute__((ext_vector_type(16))) float f32x16;

#define HPAD 258
#define CIN 256
#define COUT 512
#define KTOT 2304  // 256*9
#define NT 36      // K-tiles of 64

// workspace partition (bytes)
#define WB_BYTES (COUT * KTOT * 2)
#define XBT_OFF  WB_BYTES
#define XBT_BYTES (HPAD * HPAD * CIN * 2)
#define ABSM_OFF (XBT_OFF + XBT_BYTES)
#define ABSM_BYTES (HPAD * HPAD * 4)
#define INK_OFF  (ABSM_OFF + ABSM_BYTES)

__device__ __forceinline__ UST f2bf(float f) {
  union { float f; u32 u; } c; c.f = f;
  u32 u = c.u;
  u += 0x7FFFu + ((u >> 16) & 1u);
  return (UST)(u >> 16);
}

__device__ __forceinline__ void gload_lds16(const void* g, void* l) {
  __builtin_amdgcn_global_load_lds(
      (const __attribute__((address_space(1))) u32*)g,
      (__attribute__((address_space(3))) u32*)l, 16, 0, 0);
}

// ---- kernel 1: alpha-fold + reorder weights to [co][khkw*256+ci] bf16 ----
__global__ __launch_bounds__(256) void k_prep_w(const float* __restrict__ w,
                                                UST* __restrict__ wb) {
  int co = blockIdx.x;
  int ci = threadIdx.x;
  const float* wr = w + co * KTOT + ci * 9;
  float v[9];
  float s = 0.f;
#pragma unroll
  for (int j = 0; j < 9; ++j) { v[j] = wr[j]; s += v[j]; }
  __shared__ float red[256];
  red[ci] = s;
  __syncthreads();
#pragma unroll
  for (int off = 128; off > 0; off >>= 1) {
    if (ci < off) red[ci] += red[ci + off];
    __syncthreads();
  }
  float alpha = red[0] * (1.0f / 2304.0f);
  UST* wo = wb + co * KTOT + ci;
#pragma unroll
  for (int j = 0; j < 9; ++j) wo[j * 256] = f2bf(v[j] * alpha);
}

// ---- kernel 2: binarize + NCHW->NHWC transpose + channel-mean |x| ----
__global__ __launch_bounds__(256) void k_binz(const float* __restrict__ x,
                                              UST* __restrict__ xbt,
                                              float* __restrict__ absm) {
  int hp = blockIdx.x;
  int wt = blockIdx.y;
  int wpl = threadIdx.x & 63;
  int chunk = threadIdx.x >> 6;
  int wp = wt * 64 + wpl;
  bool valid = wp < HPAD;
  int hx = hp - 1, wx = wp - 1;
  bool inb = valid && ((unsigned)hx < 256u) && ((unsigned)wx < 256u);
  float asum = 0.f;
  u32 pk[32];
#pragma unroll
  for (int c2 = 0; c2 < 32; ++c2) {
    int ci = chunk * 64 + c2 * 2;
    float v0 = 1.0f, v1 = 1.0f;
    if (inb) {
      v0 = x[(unsigned)ci * 65536u + (unsigned)(hx * 256 + wx)];
      v1 = x[(unsigned)(ci + 1) * 65536u + (unsigned)(hx * 256 + wx)];
    }
    asum += fabsf(v0) + fabsf(v1);
    u32 s0 = (v0 >= 0.f) ? 0x3F80u : 0xBF80u;
    u32 s1 = (v1 >= 0.f) ? 0x3F80u : 0xBF80u;
    pk[c2] = s0 | (s1 << 16);
  }
  if (valid) {
    uint4* dst = (uint4*)(xbt + ((unsigned)(hp * HPAD + wp) * 256u + chunk * 64));
#pragma unroll
    for (int g = 0; g < 8; ++g)
      dst[g] = make_uint4(pk[g * 4], pk[g * 4 + 1], pk[g * 4 + 2], pk[g * 4 + 3]);
  }
  __shared__ float red[4][64];
  red[chunk][wpl] = asum;
  __syncthreads();
  if (chunk == 0 && valid) {
    float tot = red[0][wpl] + red[1][wpl] + red[2][wpl] + red[3][wpl];
    absm[hp * HPAD + wp] = tot * (1.0f / 256.0f);
  }
}

// ---- kernel 3: 3x3 box filter / 9 ----
__global__ __launch_bounds__(256) void k_inputk(const float* __restrict__ absm,
                                                float* __restrict__ inK) {
  int h = blockIdx.x, w = threadIdx.x;
  float s = 0.f;
#pragma unroll
  for (int dh = 0; dh < 3; ++dh)
#pragma unroll
    for (int dw = 0; dw < 3; ++dw) s += absm[(h + dh) * HPAD + (w + dw)];
  inK[h * 256 + w] = s * (1.0f / 9.0f);
}

// ---- kernel 4: 256x256-tile conv, 32x32x16 MFMA, ks-rotated pipeline ----
// LDS (128 KiB): A planes lds + b*32768 + P*16384; B planes +65536.
// Plane: 256 rows x 32 k bf16, superrow-XOR swizzle (verified 0-conflict):
//   (row, q[16B slot]) -> sr=row>>1, s=((row&1)<<2)|q, byte=sr*128+(s^(sr&7))*16
// 8 waves 2Mx4N; per wave 128co x 64px; 32x32x16 frags: Mrep=4, Nrep=2,
// 4 k-steps of 16 per K-tile. Frag layout: row=lane&31, k=(lane>>5)*8+j;
// C/D: col(pixel)=lane&31, row(co)=(reg&3)+8*(reg>>2)+4*(lane>>5).
// Per tile: reads(ks+1) issued before MFMA(ks) so the port drains under the
// MFMA stream; 1 barrier + 1 vmcnt(0) per tile.
#define MM32(a, b, c) __builtin_amdgcn_mfma_f32_32x32x16_bf16(a, b, c, 0, 0, 0)

#define A_LDS(B, P) (lds + (B) * 32768 + (P) * 16384)
#define B_LDS(B, P) (lds + 65536 + (B) * 32768 + (P) * 16384)
#define RD_A32(BUF, P, M, J) (*(const short8*)(A_LDS(BUF, P) + swzA[M][J]))
#define RD_B32(BUF, P, N, J) (*(const short8*)(B_LDS(BUF, P) + swzB[N][J]))

#define STAGE_A(SRC, P, BUF) do { \
    const char* s_ = (SRC) + (P) * 64; \
    char* d_ = A_LDS(BUF, P) + wv * 1024; \
    gload_lds16(s_ + aoff0, d_); \
    gload_lds16(s_ + aoff1, d_ + 8192); } while (0)

#define STAGE_B(SRC, P, BUF) do { \
    const char* s_ = (SRC) + (P) * 64; \
    char* d_ = B_LDS(BUF, P) + wv * 1024; \
    gload_lds16(s_ + boff0, d_); \
    gload_lds16(s_ + boff1, d_ + 8192); } while (0)

#define RD_PHASE(DA, DB, BUF, P, J) \
  DB[0] = RD_B32(BUF, P, 0, J); DB[1] = RD_B32(BUF, P, 1, J); \
  DA[0] = RD_A32(BUF, P, 0, J); DA[1] = RD_A32(BUF, P, 1, J); \
  DA[2] = RD_A32(BUF, P, 2, J); DA[3] = RD_A32(BUF, P, 3, J);

#define MFMA8(AF, BF) \
  __builtin_amdgcn_s_setprio(1); \
  _Pragma("unroll") for (int m = 0; m < 4; ++m) \
  _Pragma("unroll") for (int n = 0; n < 2; ++n) \
    acc[m][n] = MM32(AF[m], BF[n], acc[m][n]); \
  __builtin_amdgcn_s_setprio(0);

#define BODY(CUR, ASRC, BSRC) do { \
  short8 aX[4], bX[2], aY[4], bY[2]; \
  RD_PHASE(aX, bX, CUR, 0, 0); \
  STAGE_A((ASRC), 0, (CUR) ^ 1); STAGE_A((ASRC), 1, (CUR) ^ 1); \
  STAGE_B((BSRC), 0, (CUR) ^ 1); STAGE_B((BSRC), 1, (CUR) ^ 1); \
  __builtin_amdgcn_sched_barrier(0); \
  RD_PHASE(aY, bY, CUR, 0, 1); \
  __builtin_amdgcn_sched_barrier(0); \
  MFMA8(aX, bX); \
  RD_PHASE(aX, bX, CUR, 1, 0); \
  __builtin_amdgcn_sched_barrier(0); \
  MFMA8(aY, bY); \
  RD_PHASE(aY, bY, CUR, 1, 1); \
  __builtin_amdgcn_sched_barrier(0); \
  MFMA8(aX, bX); \
  MFMA8(aY, bY); \
  asm volatile("s_waitcnt vmcnt(0)" ::: "memory"); \
  __builtin_amdgcn_s_barrier(); \
} while (0)

#define BODY_LAST(CUR) do { \
  short8 aX[4], bX[2], aY[4], bY[2]; \
  RD_PHASE(aX, bX, CUR, 0, 0); \
  RD_PHASE(aY, bY, CUR, 0, 1); \
  __builtin_amdgcn_sched_barrier(0); \
  MFMA8(aX, bX); \
  RD_PHASE(aX, bX, CUR, 1, 0); \
  __builtin_amdgcn_sched_barrier(0); \
  MFMA8(aY, bY); \
  RD_PHASE(aY, bY, CUR, 1, 1); \
  __builtin_amdgcn_sched_barrier(0); \
  MFMA8(aX, bX); \
  MFMA8(aY, bY); \
} while (0)

__global__ __launch_bounds__(512, 2) void k_conv8(const UST* __restrict__ wb,
                                                  const UST* __restrict__ xbt,
                                                  const float* __restrict__ inK,
                                                  float* __restrict__ out) {
  __shared__ __align__(16) char lds[131072];
  int tid = threadIdx.x;
  int lane = tid & 63;
  int wv = tid >> 6;
  int wm = wv >> 2, wn = wv & 3;
  int bid = blockIdx.x;
  int bs = (bid & 7) * 64 + (bid >> 3);  // XCD-bijective swizzle (512 % 8 == 0)
  int mt = bs & 1;
  int h = bs >> 1;
  int co0 = mt << 8;

  // staging per-thread offsets (inverse-swizzled global source, linear LDS dest)
  int aoff0, aoff1, boff0, boff1;
  {
    u32 ql0 = (u32)tid * 16u, ql1 = (u32)(512 + tid) * 16u;
    u32 sr0 = ql0 >> 7, s0 = ((ql0 >> 4) & 7u) ^ (sr0 & 7u);
    u32 row0 = (sr0 << 1) | (s0 >> 2), q0 = s0 & 3u;
    u32 sr1 = ql1 >> 7, s1 = ((ql1 >> 4) & 7u) ^ (sr1 & 7u);
    u32 row1 = (sr1 << 1) | (s1 >> 2), q1 = s1 & 3u;
    aoff0 = (co0 + (int)row0) * 4608 + (int)q0 * 16;
    aoff1 = (co0 + (int)row1) * 4608 + (int)q1 * 16;
    boff0 = (int)row0 * 512 + (int)q0 * 16;
    boff1 = (int)row1 * 512 + (int)q1 * 16;
  }
  // ds_read swizzled offsets within a plane: [frag][k16-within-plane]
  int swzA[4][2], swzB[2][2];
#pragma unroll
  for (int m = 0; m < 4; ++m)
#pragma unroll
    for (int j = 0; j < 2; ++j) {
      u32 row = (u32)(wm * 128 + m * 32 + (lane & 31));
      u32 q = (u32)(j * 2 + (lane >> 5));
      u32 sr = row >> 1, s = ((row & 1u) << 2) | q;
      swzA[m][j] = (int)(sr * 128u + (s ^ (sr & 7u)) * 16u);
    }
#pragma unroll
  for (int n = 0; n < 2; ++n)
#pragma unroll
    for (int j = 0; j < 2; ++j) {
      u32 row = (u32)(wn * 64 + n * 32 + (lane & 31));
      u32 q = (u32)(j * 2 + (lane >> 5));
      u32 sr = row >> 1, s = ((row & 1u) << 2) | q;
      swzB[n][j] = (int)(sr * 128u + (s ^ (sr & 7u)) * 16u);
    }

  const char* wb_b = (const char*)wb;
  const char* xbt_b = (const char*)xbt;

  f32x16 acc[4][2];
#pragma unroll
  for (int m = 0; m < 4; ++m)
#pragma unroll
    for (int n = 0; n < 2; ++n)
#pragma unroll
      for (int r = 0; r < 16; ++r) acc[m][n][r] = 0.f;

  // prologue: stage tile 0 into buf 0
  {
    const char* b0src = xbt_b + (h * HPAD) * 512;  // kh=0, kw=0, c-chunk 0
    STAGE_A(wb_b, 0, 0); STAGE_A(wb_b, 1, 0);
    STAGE_B(b0src, 0, 0); STAGE_B(b0src, 1, 0);
  }
  asm volatile("s_waitcnt vmcnt(0)" ::: "memory");
  __builtin_amdgcn_s_barrier();

  // main: 8 khkw groups of 4 tiles (t = 0..31)
  int kh = 0, kw = 0;
  const char* bcur = xbt_b + (h * HPAD) * 512;
  for (int it = 0; it < 8; ++it) {
    int nkw = kw + 1, nkh = kh;
    if (nkw == 3) { nkw = 0; ++nkh; }
    const char* bnext = xbt_b + ((h + nkh) * HPAD + nkw) * 512;
    const char* acur = wb_b + it * 512;
    BODY(0, acur + 128, bcur + 128);  // t=4it+0, stages t+1
    BODY(1, acur + 256, bcur + 256);  // t=4it+1
    BODY(0, acur + 384, bcur + 384);  // t=4it+2
    BODY(1, acur + 512, bnext);       // t=4it+3, stages next group
    kh = nkh; kw = nkw; bcur = bnext;
  }
  // khkw = 8 (kh=2, kw=2): t = 32..35
  {
    const char* acur = wb_b + 8 * 512;
    BODY(0, acur + 128, bcur + 128);  // t=32
    BODY(1, acur + 256, bcur + 256);  // t=33
    BODY(0, acur + 384, bcur + 384);  // t=34
    BODY_LAST(1);                     // t=35
  }

  // epilogue: scale by input_K, write NCHW
  // C/D 32x32: col(pixel)=lane&31, row(co)=(r&3)+8*(r>>2)+4*(lane>>5)
  int pixbase = h * 256;
  int colp = lane & 31;
  int rbase = 4 * (lane >> 5);
#pragma unroll
  for (int n = 0; n < 2; ++n) {
    int w = wn * 64 + n * 32 + colp;
    float kv = inK[pixbase + w];
#pragma unroll
    for (int m = 0; m < 4; ++m) {
      int cobase = co0 + wm * 128 + m * 32 + rbase;
#pragma unroll
      for (int r = 0; r < 16; ++r) {
        int co = cobase + (r & 3) + 8 * (r >> 2);
        out[(u32)co * 65536u + (u32)(pixbase + w)] = acc[m][n][r] * kv;
      }
    }
  }
}

extern "C" void kernel_launch(void* const* d_in, const int* in_sizes, int n_in,
                              void* d_out, int out_size, void* d_ws, size_t ws_size,
                              hipStream_t stream) {
  const float* x = (const float*)d_in[0];
  const float* w = (const float*)d_in[1];
  float* out = (float*)d_out;
  char* ws = (char*)d_ws;
  UST* wb = (UST*)ws;
  UST* xbt = (UST*)(ws + XBT_OFF);
  float* absm = (float*)(ws + ABSM_OFF);
  float* inK = (float*)(ws + INK_OFF);

  k_prep_w<<<COUT, 256, 0, stream>>>(w, wb);
  k_binz<<<dim3(HPAD, 5), 256, 0, stream>>>(x, xbt, absm);
  k_inputk<<<256, 256, 0, stream>>>(absm, inK);
  k_conv8<<<512, 512, 0, stream>>>(wb, xbt, inK, out);
}